// Round 4
// baseline (804.880 us; speedup 1.0000x reference)
//
#include <hip/hip_runtime.h>

#define HH 192
#define WW 192
#define CC 128
#define BB 8
#define HW (HH * WW)          // 36864
#define OC 8
#define NPIX (BB * HW)        // 294912 elements per BN channel

typedef __attribute__((ext_vector_type(8))) short bf16x8;
typedef __attribute__((ext_vector_type(4))) float f32x4;

__device__ __forceinline__ unsigned short f2bf(float f) {
    unsigned int u = __float_as_uint(f);
    u += 0x7fffu + ((u >> 16) & 1u);          // RNE
    return (unsigned short)(u >> 16);
}

// ---------------------------------------------------------------------------
// T0: fp32 [b][c][h][w] -> bf16 [b][h][w][c] (c-contiguous for MFMA frags)
// ---------------------------------------------------------------------------
__global__ __launch_bounds__(256) void k_transpose(
    const float* __restrict__ x0, const float* __restrict__ x1,
    unsigned short* __restrict__ ws)
{
    const int h = blockIdx.x, b = blockIdx.y, t = blockIdx.z;
    const float* src = t ? x1 : x0;
    unsigned short* dst = ws + (size_t)t * ((size_t)BB * HH * WW * CC);
    __shared__ unsigned short lds[WW * 130];

    for (int idx = threadIdx.x; idx < CC * WW; idx += 256) {
        const int w = idx % WW, c = idx / WW;     // lanes: consecutive w -> coalesced
        const float v = src[((size_t)(b * CC + c) * HH + h) * WW + w];
        lds[w * 130 + c] = f2bf(v);
    }
    __syncthreads();
    unsigned int* dw = (unsigned int*)(dst + (size_t)(b * HH + h) * WW * CC);
    for (int idx = threadIdx.x; idx < WW * (CC / 2); idx += 256) {
        const int w = idx / (CC / 2), cp = idx % (CC / 2);  // lanes: consecutive cp
        const unsigned int lo = lds[w * 130 + 2 * cp];
        const unsigned int hi = lds[w * 130 + 2 * cp + 1];
        dw[w * (CC / 2) + cp] = lo | (hi << 16);
    }
}

// ---------------------------------------------------------------------------
// Fragment load / consume for the band-GEMM. Per wave: ut = wave (u0 fixed),
// step s in [0,16): ir = s>>1, par = s&1. 12 loads per step, 8 MFMAs.
// ---------------------------------------------------------------------------
__device__ __forceinline__ void load_frags(
    bf16x8 (&fa)[4], bf16x8 (&fb)[2][4],
    const unsigned short* __restrict__ x0b, const unsigned short* __restrict__ x1b,
    int i0, int u0, int ln15, int kg, int pi, int s)
{
    const int ir = s >> 1, par = s & 1;
    const int i  = i0 - 1 + ir;
    const int r  = i + 2 * pi - 10;
    const int icl = min(max(i, 0), HH - 1);
    const int rcl = min(max(r, 0), HH - 1);

    const unsigned short* pa =
        x0b + ((size_t)(icl * WW + (2 * (u0 + ln15) + par))) * CC + kg * 8;
    fa[0] = *(const bf16x8*)(pa);
    fa[1] = *(const bf16x8*)(pa + 32);
    fa[2] = *(const bf16x8*)(pa + 64);
    fa[3] = *(const bf16x8*)(pa + 96);

#pragma unroll
    for (int vt = 0; vt < 2; ++vt) {
        const int v   = u0 - 8 + vt * 16 + ln15;
        const int vcl = min(max(v, 0), 95);
        const unsigned short* pb =
            x1b + ((size_t)(rcl * WW + (2 * vcl + par))) * CC + kg * 8;
        fb[vt][0] = *(const bf16x8*)(pb);
        fb[vt][1] = *(const bf16x8*)(pb + 32);
        fb[vt][2] = *(const bf16x8*)(pb + 64);
        fb[vt][3] = *(const bf16x8*)(pb + 96);
    }
}

__device__ __forceinline__ void consume_frags(
    const bf16x8 (&fa)[4], const bf16x8 (&fb)[2][4],
    float (&corr)[8][194][11],
    int i0, int u0, int ln15, int kg, int pi, int s)
{
    const int ir = s >> 1, par = s & 1;
    const int i  = i0 - 1 + ir;
    const int r  = i + 2 * pi - 10;
    const bool gv = (i >= 0) && (i < HH) && (r >= 0) && (r < HH);

#pragma unroll
    for (int vt = 0; vt < 2; ++vt) {
        f32x4 c = {0.f, 0.f, 0.f, 0.f};
        c = __builtin_amdgcn_mfma_f32_16x16x32_bf16(fa[0], fb[vt][0], c, 0, 0, 0);
        c = __builtin_amdgcn_mfma_f32_16x16x32_bf16(fa[1], fb[vt][1], c, 0, 0, 0);
        c = __builtin_amdgcn_mfma_f32_16x16x32_bf16(fa[2], fb[vt][2], c, 0, 0, 0);
        c = __builtin_amdgcn_mfma_f32_16x16x32_bf16(fa[3], fb[vt][3], c, 0, 0, 0);

        const int v  = u0 - 8 + vt * 16 + ln15;
        const bool lv = gv && (v >= 0) && (v < 96);
#pragma unroll
        for (int rg = 0; rg < 4; ++rg) {
            const int u  = u0 + kg * 4 + rg;
            const int pj = v - u + 5;
            if (pj >= 0 && pj < 11)
                corr[ir][2 * u + par + 1][pj] = lv ? c[rg] : 0.f;
        }
    }
}

// ---------------------------------------------------------------------------
// K1-MFMA v3: strip of 6 output rows (8 corr rows), 6 waves (ut = wave),
// software-pipelined fragment loads (double-buffered, prefetch crosses the
// conv phase into the next pi), fp32 corr LDS [8][194][11] (68 KB, 2 blk/CU).
// ---------------------------------------------------------------------------
__global__ __launch_bounds__(384, 3) void k_corr_mfma_conv(
    const unsigned short* __restrict__ x0t, const unsigned short* __restrict__ x1t,
    const float* __restrict__ cw, const float* __restrict__ cb,
    float* __restrict__ y)
{
    const int b    = blockIdx.y;
    const int i0   = blockIdx.x * 6;
    const int tid  = threadIdx.x;
    const int wave = tid >> 6, lane = tid & 63;
    const int ln15 = lane & 15, kg = lane >> 4;
    const int u0   = wave * 16;

    __shared__ float corr[8][194][11];    // jj = col+1; cols 0,193 stay zero

    if (tid < 176) {                       // zero the pad columns once
        const int ir = tid / 22, rem = tid % 22;
        const int pj = rem % 11, jj = (rem < 11) ? 0 : 193;
        corr[ir][jj][pj] = 0.f;
    }

    float yacc[3][OC];
#pragma unroll
    for (int k = 0; k < 3; ++k)
#pragma unroll
        for (int o = 0; o < OC; ++o) yacc[k][o] = 0.f;

    const int jt  = tid % 192;             // conv: column
    const int irb = tid / 192;             // conv: 0/1; output rows irb,irb+2,irb+4

    const size_t ibase = (size_t)b * HH * WW * CC;
    const unsigned short* x0b = x0t + ibase;
    const unsigned short* x1b = x1t + ibase;

    bf16x8 fa0[4], fa1[4];
    bf16x8 fb0[2][4], fb1[2][4];

    load_frags(fa0, fb0, x0b, x1b, i0, u0, ln15, kg, 0, 0);

    for (int pi = 0; pi < 11; ++pi) {
        __syncthreads();                   // conv(pi-1) done reading corr

        // ---- MFMA band-GEMM phase: 16 steps, pipelined ----
#pragma unroll
        for (int sp = 0; sp < 8; ++sp) {
            const int s0 = 2 * sp, s1 = 2 * sp + 1;
            load_frags(fa1, fb1, x0b, x1b, i0, u0, ln15, kg, pi, s1);
            consume_frags(fa0, fb0, corr, i0, u0, ln15, kg, pi, s0);
            const int pin = (sp == 7) ? min(pi + 1, 10) : pi;
            const int s2  = (sp == 7) ? 0 : s1 + 1;
            load_frags(fa0, fb0, x0b, x1b, i0, u0, ln15, kg, pin, s2);
            consume_frags(fa1, fb1, corr, i0, u0, ln15, kg, pi, s1);
        }
        __syncthreads();                   // corr slice visible

        // ---- conv(3x3, 121->8) VALU phase, 3 px/thread ----
        for (int ki = 0; ki < 3; ++ki) {
            for (int kj = 0; kj < 3; ++kj) {
                float cv[3][11];
#pragma unroll
                for (int k = 0; k < 3; ++k) {
                    const float* cp = &corr[irb + 2 * k + ki][jt + kj][0];
#pragma unroll
                    for (int pj = 0; pj < 11; ++pj) cv[k][pj] = cp[pj];
                }
#pragma unroll
                for (int o = 0; o < OC; ++o) {
                    float y0 = yacc[0][o], y1 = yacc[1][o], y2 = yacc[2][o];
#pragma unroll
                    for (int pj = 0; pj < 11; ++pj) {
                        const float wv =              // wave-uniform -> s_load
                            cw[o * 1089 + (pi * 11 + pj) * 9 + ki * 3 + kj];
                        y0 = fmaf(wv, cv[0][pj], y0);
                        y1 = fmaf(wv, cv[1][pj], y1);
                        y2 = fmaf(wv, cv[2][pj], y2);
                    }
                    yacc[0][o] = y0; yacc[1][o] = y1; yacc[2][o] = y2;
                }
            }
        }
    }

#pragma unroll
    for (int k = 0; k < 3; ++k) {
        const int irow = i0 + irb + 2 * k;
#pragma unroll
        for (int o = 0; o < OC; ++o)
            y[((size_t)(b * OC + o) * HH + irow) * WW + jt] = yacc[k][o] + cb[o];
    }
}

// ---------------------------------------------------------------------------
// Fallback K1 (round-1 verified fp32 path) — only if ws too small
// ---------------------------------------------------------------------------
__global__ __launch_bounds__(256) void k_corr_conv(
    const float* __restrict__ x0, const float* __restrict__ x1,
    const float* __restrict__ cw, const float* __restrict__ cb,
    float* __restrict__ y)
{
    const int b  = blockIdx.z;
    const int i0 = blockIdx.y * 14;
    const int j0 = blockIdx.x * 14;
    const int li = threadIdx.x >> 4;
    const int lj = threadIdx.x & 15;
    const int gi = i0 + li - 1;
    const int gj = j0 + lj - 1;
    const bool valid    = (gi >= 0) & (gi < HH) & (gj >= 0) & (gj < WW);
    const bool interior = (li >= 1) & (li <= 14) & (lj >= 1) & (lj <= 14)
                        & (gi < HH) & (gj < WW);

    __shared__ float corr[16][16][13];

    float yacc[OC];
#pragma unroll
    for (int o = 0; o < OC; ++o) yacc[o] = 0.f;

    const size_t bbase = (size_t)b * CC * HW;
    const float* x0p = x0 + bbase + (size_t)gi * WW + gj;

    for (int pi = 0; pi < 11; ++pi) {
        float acc[11];
#pragma unroll
        for (int k = 0; k < 11; ++k) acc[k] = 0.f;

        const int r = gi + 2 * pi - 10;
        if (valid && r >= 0 && r < HH) {
            const float* p0 = x0p;
            if (gj >= 10 && gj <= WW - 11) {
                const float* p1o = x1 + bbase + (size_t)r * WW + (gj - 10);
#pragma unroll 2
                for (int c = 0; c < CC; ++c) {
                    const float a = *p0;
#pragma unroll
                    for (int k = 0; k < 11; ++k)
                        acc[k] = fmaf(a, p1o[2 * k], acc[k]);
                    p0 += HW; p1o += HW;
                }
            } else {
                const float* p1 = x1 + bbase + (size_t)r * WW;
#pragma unroll 2
                for (int c = 0; c < CC; ++c) {
                    const float a = *p0;
#pragma unroll
                    for (int k = 0; k < 11; ++k) {
                        const int col = gj + 2 * k - 10;
                        const float v = (col >= 0 && col < WW) ? p1[col] : 0.f;
                        acc[k] = fmaf(a, v, acc[k]);
                    }
                    p0 += HW; p1 += HW;
                }
            }
        }

        __syncthreads();
#pragma unroll
        for (int k = 0; k < 11; ++k) corr[li][lj][k] = acc[k];
        __syncthreads();

        if (interior) {
#pragma unroll
            for (int ki = 0; ki < 3; ++ki) {
#pragma unroll
                for (int kj = 0; kj < 3; ++kj) {
                    float cv[11];
#pragma unroll
                    for (int k = 0; k < 11; ++k)
                        cv[k] = corr[li + ki - 1][lj + kj - 1][k];
#pragma unroll
                    for (int o = 0; o < OC; ++o) {
#pragma unroll
                        for (int k = 0; k < 11; ++k) {
                            const float wv =
                                cw[(((o * 121) + pi * 11 + k) * 3 + ki) * 3 + kj];
                            yacc[o] = fmaf(wv, cv[k], yacc[o]);
                        }
                    }
                }
            }
        }
    }

    if (interior) {
#pragma unroll
        for (int o = 0; o < OC; ++o)
            y[(size_t)(b * OC + o) * HW + (size_t)gi * WW + gj] = yacc[o] + cb[o];
    }
}

// ---------------------------------------------------------------------------
// BN stats (256 partial blocks) + finalize + apply
// ---------------------------------------------------------------------------
__global__ __launch_bounds__(256) void k_stats_partial(
    const float* __restrict__ y, float* __restrict__ ws)
{
    const int bid = blockIdx.x;            // b*32 + o*4 + q
    const int b = bid >> 5, rem = bid & 31;
    const int o = rem >> 2, q = rem & 3;
    const float4* p = (const float4*)(y + (size_t)(b * OC + o) * HW) + q * (HW / 16);
    float s = 0.f, qq = 0.f;
    for (int t = threadIdx.x; t < HW / 16; t += 256) {
        const float4 v = p[t];
        s += v.x + v.y + v.z + v.w;
        qq = fmaf(v.x, v.x, qq); qq = fmaf(v.y, v.y, qq);
        qq = fmaf(v.z, v.z, qq); qq = fmaf(v.w, v.w, qq);
    }
#pragma unroll
    for (int off = 32; off > 0; off >>= 1) {
        s  += __shfl_down(s, off);
        qq += __shfl_down(qq, off);
    }
    __shared__ float ss[4], sq[4];
    const int lane = threadIdx.x & 63, wv = threadIdx.x >> 6;
    if (lane == 0) { ss[wv] = s; sq[wv] = qq; }
    __syncthreads();
    if (threadIdx.x == 0) {
        ws[bid]       = ss[0] + ss[1] + ss[2] + ss[3];
        ws[256 + bid] = sq[0] + sq[1] + sq[2] + sq[3];
    }
}

__global__ void k_stats_final(float* __restrict__ ws,
                              const float* __restrict__ gamma,
                              const float* __restrict__ beta)
{
    const int o = threadIdx.x;
    if (o < 8) {
        float S = 0.f, Q = 0.f;
#pragma unroll
        for (int b = 0; b < 8; ++b)
#pragma unroll
            for (int q = 0; q < 4; ++q) {
                S += ws[b * 32 + o * 4 + q];
                Q += ws[256 + b * 32 + o * 4 + q];
            }
        const float invN = 1.f / (float)NPIX;
        const float mean = S * invN;
        const float var  = Q * invN - mean * mean;
        const float sc   = gamma[o] / sqrtf(var + 1e-5f);
        ws[512 + o] = sc;
        ws[520 + o] = beta[o] - mean * sc;
    }
}

__global__ __launch_bounds__(256) void k_bn_relu(
    float* __restrict__ y, const float* __restrict__ ws)
{
    const int i = blockIdx.x * 256 + threadIdx.x;
    const int o = (i / (HW / 4)) & 7;
    const float sc = ws[512 + o], sh = ws[520 + o];
    float4 v = ((float4*)y)[i];
    v.x = fmaxf(fmaf(v.x, sc, sh), 0.f);
    v.y = fmaxf(fmaf(v.y, sc, sh), 0.f);
    v.z = fmaxf(fmaf(v.z, sc, sh), 0.f);
    v.w = fmaxf(fmaf(v.w, sc, sh), 0.f);
    ((float4*)y)[i] = v;
}

extern "C" void kernel_launch(void* const* d_in, const int* in_sizes, int n_in,
                              void* d_out, int out_size, void* d_ws, size_t ws_size,
                              hipStream_t stream)
{
    const float* x0    = (const float*)d_in[0];
    const float* x1    = (const float*)d_in[1];
    const float* cw    = (const float*)d_in[2];
    const float* cb    = (const float*)d_in[3];
    const float* gamma = (const float*)d_in[4];
    const float* beta  = (const float*)d_in[5];
    float* y  = (float*)d_out;
    float* ws = (float*)d_ws;

    const size_t need = (size_t)2 * BB * HH * WW * CC * sizeof(unsigned short); // 151 MB

    if (ws_size >= need) {
        unsigned short* x0t = (unsigned short*)d_ws;
        unsigned short* x1t = x0t + (size_t)BB * HH * WW * CC;
        k_transpose<<<dim3(HH, BB, 2), 256, 0, stream>>>(x0, x1, (unsigned short*)d_ws);
        k_corr_mfma_conv<<<dim3(32, BB), 384, 0, stream>>>(x0t, x1t, cw, cb, y);
    } else {
        dim3 g1(14, 14, 8);
        k_corr_conv<<<g1, 256, 0, stream>>>(x0, x1, cw, cb, y);
    }
    k_stats_partial<<<256, 256, 0, stream>>>(y, ws);
    k_stats_final<<<1, 64, 0, stream>>>(ws, gamma, beta);
    k_bn_relu<<<(OC * BB * HW / 4) / 256, 256, 0, stream>>>(y, ws);
}

// Round 5
// 655.383 us; speedup vs baseline: 1.2281x; 1.2281x over previous
//
#include <hip/hip_runtime.h>

#define HH 192
#define WW 192
#define CC 128
#define BB 8
#define HW (HH * WW)          // 36864
#define OC 8
#define NPIX (BB * HW)        // 294912 elements per BN channel
#define YCHUNK (OC * BB * HW) // elements per partial-y buffer

typedef __attribute__((ext_vector_type(8))) short bf16x8;
typedef __attribute__((ext_vector_type(4))) float f32x4;

__device__ __forceinline__ unsigned short f2bf(float f) {
    unsigned int u = __float_as_uint(f);
    u += 0x7fffu + ((u >> 16) & 1u);          // RNE
    return (unsigned short)(u >> 16);
}
__device__ __forceinline__ float bf2f(unsigned short u) {
    return __uint_as_float(((unsigned int)u) << 16);
}

// ---------------------------------------------------------------------------
// T0: fp32 [b][c][h][w] -> bf16 [b][h][w][c] (c-contiguous for MFMA frags)
// ---------------------------------------------------------------------------
__global__ __launch_bounds__(256) void k_transpose(
    const float* __restrict__ x0, const float* __restrict__ x1,
    unsigned short* __restrict__ ws)
{
    const int h = blockIdx.x, b = blockIdx.y, t = blockIdx.z;
    const float* src = t ? x1 : x0;
    unsigned short* dst = ws + (size_t)t * ((size_t)BB * HH * WW * CC);
    __shared__ unsigned short lds[WW * 130];

    for (int idx = threadIdx.x; idx < CC * WW; idx += 256) {
        const int w = idx % WW, c = idx / WW;     // lanes: consecutive w -> coalesced
        const float v = src[((size_t)(b * CC + c) * HH + h) * WW + w];
        lds[w * 130 + c] = f2bf(v);
    }
    __syncthreads();
    unsigned int* dw = (unsigned int*)(dst + (size_t)(b * HH + h) * WW * CC);
    for (int idx = threadIdx.x; idx < WW * (CC / 2); idx += 256) {
        const int w = idx / (CC / 2), cp = idx % (CC / 2);  // lanes: consecutive cp
        const unsigned int lo = lds[w * 130 + 2 * cp];
        const unsigned int hi = lds[w * 130 + 2 * cp + 1];
        dw[w * (CC / 2) + cp] = lo | (hi << 16);
    }
}

// ---------------------------------------------------------------------------
// K1-MFMA v5 = r2 structure (6-row strip, 6 waves, bf16 corr LDS) + pi-split:
// grid = 256*split blocks; each block does its pi-chunk and accumulates into
// a private partial-y. XCD swizzle: batch image b pinned to XCD b, part-major
// so concurrent blocks share the x1 row window in that XCD's L2.
// ---------------------------------------------------------------------------
__global__ __launch_bounds__(384) void k_corr_mfma_conv(
    const unsigned short* __restrict__ x0t, const unsigned short* __restrict__ x1t,
    const float* __restrict__ cw, const float* __restrict__ cb,
    float* __restrict__ yparts, int split)
{
    const int N = 256 * split;
    const int L = blockIdx.x;
    const int w = (L & 7) * (N >> 3) + (L >> 3);   // bijective: N % 8 == 0
    const int b     = w / (32 * split);
    const int rem   = w % (32 * split);
    const int part  = rem >> 5;                     // part-major within b
    const int strip = rem & 31;
    const int i0    = strip * 6;
    const int plo   = (11 * part) / split;
    const int phi   = (11 * (part + 1)) / split;

    const int tid  = threadIdx.x;
    const int wave = tid >> 6, lane = tid & 63;
    const int ln15 = lane & 15, kg = lane >> 4;

    __shared__ unsigned short corr[8][194][11];   // jj = col+1; cols 0,193 zero

    if (tid < 176) {                               // zero the pad columns once
        const int ir = tid / 22, rr = tid % 22;
        const int pj = rr % 11, jj = (rr < 11) ? 0 : 193;
        corr[ir][jj][pj] = 0;
    }

    float yacc[3][OC];
#pragma unroll
    for (int k = 0; k < 3; ++k)
#pragma unroll
        for (int o = 0; o < OC; ++o) yacc[k][o] = 0.f;

    const int jt  = tid % 192;             // conv: column
    const int irb = tid / 192;             // conv: 0/1; rows irb, irb+2, irb+4

    const size_t ibase = (size_t)b * HH * WW * CC;
    const unsigned short* x0b = x0t + ibase;
    const unsigned short* x1b = x1t + ibase;

    for (int pi = plo; pi < phi; ++pi) {
        __syncthreads();                   // conv(pi-1) done reading corr

        // ---------------- MFMA band-GEMM phase: 96 groups ----------------
        for (int g = wave; g < 96; g += 6) {
            const int ir  = g / 12, rr = g % 12;
            const int par = rr / 6, ut = rr % 6;
            const int u0  = ut * 16;
            const int i   = i0 - 1 + ir;
            const int r   = i + 2 * pi - 10;
            const bool gv = (i >= 0) && (i < HH) && (r >= 0) && (r < HH);
            const int icl = min(max(i, 0), HH - 1);
            const int rcl = min(max(r, 0), HH - 1);

            const unsigned short* pa =
                x0b + ((size_t)(icl * WW + (2 * (u0 + ln15) + par))) * CC + kg * 8;
            const bf16x8 a0 = *(const bf16x8*)(pa);
            const bf16x8 a1 = *(const bf16x8*)(pa + 32);
            const bf16x8 a2 = *(const bf16x8*)(pa + 64);
            const bf16x8 a3 = *(const bf16x8*)(pa + 96);

#pragma unroll
            for (int vt = 0; vt < 2; ++vt) {
                const int v0  = u0 - 8 + vt * 16;
                const int v   = v0 + ln15;
                const int vcl = min(max(v, 0), 95);
                const unsigned short* pb =
                    x1b + ((size_t)(rcl * WW + (2 * vcl + par))) * CC + kg * 8;
                const bf16x8 b0 = *(const bf16x8*)(pb);
                const bf16x8 b1 = *(const bf16x8*)(pb + 32);
                const bf16x8 b2 = *(const bf16x8*)(pb + 64);
                const bf16x8 b3 = *(const bf16x8*)(pb + 96);

                f32x4 c = {0.f, 0.f, 0.f, 0.f};
                c = __builtin_amdgcn_mfma_f32_16x16x32_bf16(a0, b0, c, 0, 0, 0);
                c = __builtin_amdgcn_mfma_f32_16x16x32_bf16(a1, b1, c, 0, 0, 0);
                c = __builtin_amdgcn_mfma_f32_16x16x32_bf16(a2, b2, c, 0, 0, 0);
                c = __builtin_amdgcn_mfma_f32_16x16x32_bf16(a3, b3, c, 0, 0, 0);

                const bool lv = gv && (v >= 0) && (v < 96);
#pragma unroll
                for (int rg = 0; rg < 4; ++rg) {
                    const int u  = u0 + kg * 4 + rg;
                    const int pj = v - u + 5;
                    if (pj >= 0 && pj < 11)
                        corr[ir][2 * u + par + 1][pj] = f2bf(lv ? c[rg] : 0.f);
                }
            }
        }
        __syncthreads();                   // corr slice visible

        // ---------------- conv(3x3, 121->8) VALU phase, 3 px/thread -------
        for (int ki = 0; ki < 3; ++ki) {
            for (int kj = 0; kj < 3; ++kj) {
                float cv[3][11];
#pragma unroll
                for (int k = 0; k < 3; ++k) {
                    const unsigned short* cp = &corr[irb + 2 * k + ki][jt + kj][0];
#pragma unroll
                    for (int pj = 0; pj < 11; ++pj) cv[k][pj] = bf2f(cp[pj]);
                }
#pragma unroll
                for (int o = 0; o < OC; ++o) {
                    float y0 = yacc[0][o], y1 = yacc[1][o], y2 = yacc[2][o];
#pragma unroll
                    for (int pj = 0; pj < 11; ++pj) {
                        const float wv =              // wave-uniform -> s_load
                            cw[(((o * 121) + pi * 11 + pj) * 3 + ki) * 3 + kj];
                        y0 = fmaf(wv, cv[0][pj], y0);
                        y1 = fmaf(wv, cv[1][pj], y1);
                        y2 = fmaf(wv, cv[2][pj], y2);
                    }
                    yacc[0][o] = y0; yacc[1][o] = y1; yacc[2][o] = y2;
                }
            }
        }
    }

    float* yp = yparts + (size_t)part * YCHUNK;
#pragma unroll
    for (int k = 0; k < 3; ++k) {
        const int irow = i0 + irb + 2 * k;
#pragma unroll
        for (int o = 0; o < OC; ++o) {
            float val = yacc[k][o];
            if (part == 0) val += cb[o];           // bias once
            yp[((size_t)(b * OC + o) * HH + irow) * WW + jt] = val;
        }
    }
}

// ---------------------------------------------------------------------------
// Fallback K1 (round-1 verified fp32 path) — only if ws too small
// ---------------------------------------------------------------------------
__global__ __launch_bounds__(256) void k_corr_conv(
    const float* __restrict__ x0, const float* __restrict__ x1,
    const float* __restrict__ cw, const float* __restrict__ cb,
    float* __restrict__ y)
{
    const int b  = blockIdx.z;
    const int i0 = blockIdx.y * 14;
    const int j0 = blockIdx.x * 14;
    const int li = threadIdx.x >> 4;
    const int lj = threadIdx.x & 15;
    const int gi = i0 + li - 1;
    const int gj = j0 + lj - 1;
    const bool valid    = (gi >= 0) & (gi < HH) & (gj >= 0) & (gj < WW);
    const bool interior = (li >= 1) & (li <= 14) & (lj >= 1) & (lj <= 14)
                        & (gi < HH) & (gj < WW);

    __shared__ float corr[16][16][13];

    float yacc[OC];
#pragma unroll
    for (int o = 0; o < OC; ++o) yacc[o] = 0.f;

    const size_t bbase = (size_t)b * CC * HW;
    const float* x0p = x0 + bbase + (size_t)gi * WW + gj;

    for (int pi = 0; pi < 11; ++pi) {
        float acc[11];
#pragma unroll
        for (int k = 0; k < 11; ++k) acc[k] = 0.f;

        const int r = gi + 2 * pi - 10;
        if (valid && r >= 0 && r < HH) {
            const float* p0 = x0p;
            if (gj >= 10 && gj <= WW - 11) {
                const float* p1o = x1 + bbase + (size_t)r * WW + (gj - 10);
#pragma unroll 2
                for (int c = 0; c < CC; ++c) {
                    const float a = *p0;
#pragma unroll
                    for (int k = 0; k < 11; ++k)
                        acc[k] = fmaf(a, p1o[2 * k], acc[k]);
                    p0 += HW; p1o += HW;
                }
            } else {
                const float* p1 = x1 + bbase + (size_t)r * WW;
#pragma unroll 2
                for (int c = 0; c < CC; ++c) {
                    const float a = *p0;
#pragma unroll
                    for (int k = 0; k < 11; ++k) {
                        const int col = gj + 2 * k - 10;
                        const float v = (col >= 0 && col < WW) ? p1[col] : 0.f;
                        acc[k] = fmaf(a, v, acc[k]);
                    }
                    p0 += HW; p1 += HW;
                }
            }
        }

        __syncthreads();
#pragma unroll
        for (int k = 0; k < 11; ++k) corr[li][lj][k] = acc[k];
        __syncthreads();

        if (interior) {
#pragma unroll
            for (int ki = 0; ki < 3; ++ki) {
#pragma unroll
                for (int kj = 0; kj < 3; ++kj) {
                    float cv[11];
#pragma unroll
                    for (int k = 0; k < 11; ++k)
                        cv[k] = corr[li + ki - 1][lj + kj - 1][k];
#pragma unroll
                    for (int o = 0; o < OC; ++o) {
#pragma unroll
                        for (int k = 0; k < 11; ++k) {
                            const float wv =
                                cw[(((o * 121) + pi * 11 + k) * 3 + ki) * 3 + kj];
                            yacc[o] = fmaf(wv, cv[k], yacc[o]);
                        }
                    }
                }
            }
        }
    }

    if (interior) {
#pragma unroll
        for (int o = 0; o < OC; ++o)
            y[(size_t)(b * OC + o) * HW + (size_t)gi * WW + gj] = yacc[o] + cb[o];
    }
}

// ---------------------------------------------------------------------------
// BN stats over sum of `split` partial-y buffers (deterministic, no atomics)
// ---------------------------------------------------------------------------
__global__ __launch_bounds__(256) void k_stats_partial(
    const float* __restrict__ yparts, int split, float* __restrict__ st)
{
    const int bid = blockIdx.x;            // b*32 + o*4 + q
    const int b = bid >> 5, rem = bid & 31;
    const int o = rem >> 2, q = rem & 3;
    const float4* p = (const float4*)(yparts + (size_t)(b * OC + o) * HW)
                    + q * (HW / 16);
    float s = 0.f, qq = 0.f;
    for (int t = threadIdx.x; t < HW / 16; t += 256) {
        float4 z = p[t];
        for (int pp = 1; pp < split; ++pp) {
            const float4 v = p[t + (size_t)pp * (YCHUNK / 4)];
            z.x += v.x; z.y += v.y; z.z += v.z; z.w += v.w;
        }
        s += z.x + z.y + z.z + z.w;
        qq = fmaf(z.x, z.x, qq); qq = fmaf(z.y, z.y, qq);
        qq = fmaf(z.z, z.z, qq); qq = fmaf(z.w, z.w, qq);
    }
#pragma unroll
    for (int off = 32; off > 0; off >>= 1) {
        s  += __shfl_down(s, off);
        qq += __shfl_down(qq, off);
    }
    __shared__ float ss[4], sq[4];
    const int lane = threadIdx.x & 63, wv = threadIdx.x >> 6;
    if (lane == 0) { ss[wv] = s; sq[wv] = qq; }
    __syncthreads();
    if (threadIdx.x == 0) {
        st[bid]       = ss[0] + ss[1] + ss[2] + ss[3];
        st[256 + bid] = sq[0] + sq[1] + sq[2] + sq[3];
    }
}

__global__ void k_stats_final(float* __restrict__ st,
                              const float* __restrict__ gamma,
                              const float* __restrict__ beta)
{
    const int o = threadIdx.x;
    if (o < 8) {
        float S = 0.f, Q = 0.f;
#pragma unroll
        for (int b = 0; b < 8; ++b)
#pragma unroll
            for (int q = 0; q < 4; ++q) {
                S += st[b * 32 + o * 4 + q];
                Q += st[256 + b * 32 + o * 4 + q];
            }
        const float invN = 1.f / (float)NPIX;
        const float mean = S * invN;
        const float var  = Q * invN - mean * mean;
        const float sc   = gamma[o] / sqrtf(var + 1e-5f);
        st[512 + o] = sc;
        st[520 + o] = beta[o] - mean * sc;
    }
}

// ---------------------------------------------------------------------------
// BN affine + ReLU: out = relu(scale * (sum of partials) + shift)
// ---------------------------------------------------------------------------
__global__ __launch_bounds__(256) void k_bn_relu(
    const float* __restrict__ yparts, int split,
    const float* __restrict__ st, float* __restrict__ out)
{
    const int i = blockIdx.x * 256 + threadIdx.x;     // float4 idx, exact grid
    const int o = (i / (HW / 4)) & 7;
    const float sc = st[512 + o], sh = st[520 + o];
    const float4* p = (const float4*)yparts;
    float4 z = p[i];
    for (int pp = 1; pp < split; ++pp) {
        const float4 v = p[i + (size_t)pp * (YCHUNK / 4)];
        z.x += v.x; z.y += v.y; z.z += v.z; z.w += v.w;
    }
    float4 r;
    r.x = fmaxf(fmaf(z.x, sc, sh), 0.f);
    r.y = fmaxf(fmaf(z.y, sc, sh), 0.f);
    r.z = fmaxf(fmaf(z.z, sc, sh), 0.f);
    r.w = fmaxf(fmaf(z.w, sc, sh), 0.f);
    ((float4*)out)[i] = r;
}

extern "C" void kernel_launch(void* const* d_in, const int* in_sizes, int n_in,
                              void* d_out, int out_size, void* d_ws, size_t ws_size,
                              hipStream_t stream)
{
    const float* x0    = (const float*)d_in[0];
    const float* x1    = (const float*)d_in[1];
    const float* cw    = (const float*)d_in[2];
    const float* cb    = (const float*)d_in[3];
    const float* gamma = (const float*)d_in[4];
    const float* beta  = (const float*)d_in[5];
    float* out = (float*)d_out;
    float* st  = (float*)d_ws;   // stats scratch reuses ws base (after main kernel)

    const size_t needT  = (size_t)2 * BB * HH * WW * CC * sizeof(unsigned short); // 151 MB
    const size_t ybytes = (size_t)YCHUNK * sizeof(float);                          // 9.44 MB

    if (ws_size >= needT) {
        unsigned short* x0t = (unsigned short*)d_ws;
        unsigned short* x1t = x0t + (size_t)BB * HH * WW * CC;

        int split = (int)((ws_size - needT) / ybytes);
        if (split > 4) split = 4;
        float* yparts = (split >= 2) ? (float*)((char*)d_ws + needT) : out;
        if (split < 1) split = 1;

        k_transpose<<<dim3(HH, BB, 2), 256, 0, stream>>>(x0, x1, (unsigned short*)d_ws);
        k_corr_mfma_conv<<<256 * split, 384, 0, stream>>>(x0t, x1t, cw, cb,
                                                          yparts, split);
        k_stats_partial<<<256, 256, 0, stream>>>(yparts, split, st);
        k_stats_final<<<1, 64, 0, stream>>>(st, gamma, beta);
        k_bn_relu<<<(YCHUNK / 4) / 256, 256, 0, stream>>>(yparts, split, st, out);
    } else {
        dim3 g1(14, 14, 8);
        k_corr_conv<<<g1, 256, 0, stream>>>(x0, x1, cw, cb, out);
        k_stats_partial<<<256, 256, 0, stream>>>(out, 1, st);
        k_stats_final<<<1, 64, 0, stream>>>(st, gamma, beta);
        k_bn_relu<<<(YCHUNK / 4) / 256, 256, 0, stream>>>(out, 1, st, out);
    }
}

// Round 6
// 561.120 us; speedup vs baseline: 1.4344x; 1.1680x over previous
//
#include <hip/hip_runtime.h>

#define HH 192
#define WW 192
#define CC 128
#define BB 8
#define HW (HH * WW)          // 36864
#define OC 8
#define NPIX (BB * HW)        // 294912 per BN channel
#define YCHUNK (OC * BB * HW) // elements per y buffer
#define X0ROW 24576           // elems per (b,row): 2par*6ut*2048
#define X1ROW 28672           // elems per (b,row): 2par*7vt*2048

typedef __attribute__((ext_vector_type(8))) short bf16x8;
typedef __attribute__((ext_vector_type(4))) float f32x4;

__device__ __forceinline__ unsigned short f2bf(float f) {
    unsigned int u = __float_as_uint(f);
    u += 0x7fffu + ((u >> 16) & 1u);          // RNE
    return (unsigned short)(u >> 16);
}

// ---------------------------------------------------------------------------
// k_pack: fp32 [b][c][h][w] -> bf16 fragment-ordered tiles.
// x0t[b][i]: 12 tiles (par*6+ut) of 2048 elems, tile = [q(4)][kg(4)][pxl(16)][e(8)],
//            elem (pxl,c): px = 2*(16*ut+pxl)+par, c = q*32+kg*8+e.
// x1t[b][r]: 14 tiles (par*7+vt), v = 16*vt-8+pxl, zero outside v in [0,96).
// A fragment load a_q for wave ut, lane l is then base + q*512 + l*8 (dense).
// ---------------------------------------------------------------------------
__global__ __launch_bounds__(256) void k_pack(
    const float* __restrict__ x0, const float* __restrict__ x1,
    unsigned short* __restrict__ x0t, unsigned short* __restrict__ x1t)
{
    const int h = blockIdx.x, b = blockIdx.y, t = blockIdx.z;
    const float* src = t ? x1 : x0;
    __shared__ unsigned short lds[WW * 130];

    for (int idx = threadIdx.x; idx < CC * WW; idx += 256) {
        const int w = idx % WW, c = idx / WW;      // consecutive w per lane
        lds[w * 130 + c] = f2bf(src[((size_t)(b * CC + c) * HH + h) * WW + w]);
    }
    __syncthreads();

    if (t == 0) {
        unsigned int* dst = (unsigned int*)(x0t + (size_t)(b * HH + h) * X0ROW);
        for (int f2 = threadIdx.x; f2 < X0ROW / 2; f2 += 256) {
            const int e2  = f2 & 3;
            const int pxl = (f2 >> 2) & 15;
            const int kg  = (f2 >> 6) & 3;
            const int q   = (f2 >> 8) & 3;
            const int pu  = f2 >> 10;              // par*6 + ut
            const int ut  = pu % 6, par = pu / 6;
            const int px  = 2 * (16 * ut + pxl) + par;
            const int c   = q * 32 + kg * 8 + e2 * 2;
            const unsigned int lo = lds[px * 130 + c];
            const unsigned int hi = lds[px * 130 + c + 1];
            dst[f2] = lo | (hi << 16);
        }
    } else {
        unsigned int* dst = (unsigned int*)(x1t + (size_t)(b * HH + h) * X1ROW);
        for (int f2 = threadIdx.x; f2 < X1ROW / 2; f2 += 256) {
            const int e2  = f2 & 3;
            const int pxl = (f2 >> 2) & 15;
            const int kg  = (f2 >> 6) & 3;
            const int q   = (f2 >> 8) & 3;
            const int pv  = f2 >> 10;              // par*7 + vt
            const int vt  = pv % 7, par = pv / 7;
            const int v   = 16 * vt - 8 + pxl;
            unsigned int val = 0;
            if (v >= 0 && v < 96) {
                const int px = 2 * v + par;
                const int c  = q * 32 + kg * 8 + e2 * 2;
                val = lds[px * 130 + c] | ((unsigned int)lds[px * 130 + c + 1] << 16);
            }
            dst[f2] = val;
        }
    }
}

// ---------------------------------------------------------------------------
// K1-MFMA v6: r2 geometry (6-row strip, 6 waves, wave = u-tile) with dense
// fragment-ordered loads, fp32 corr LDS [8][194][11] (stride 11: coprime 32),
// pi-split=2 across blocks (part0 -> d_out(+bias), part1 -> ws partial).
// ---------------------------------------------------------------------------
__global__ __launch_bounds__(384, 3) void k_corr_mfma_conv(
    const unsigned short* __restrict__ x0t, const unsigned short* __restrict__ x1t,
    const float* __restrict__ cw, const float* __restrict__ cb,
    float* __restrict__ y0, float* __restrict__ y1)
{
    const int L = blockIdx.x;                     // 512 blocks
    const int w = (L & 7) * 64 + (L >> 3);        // bijective XCD swizzle
    const int b     = w >> 6;                     // image b pinned to XCD b
    const int rem   = w & 63;
    const int part  = rem >> 5;                   // part-major within b
    const int strip = rem & 31;
    const int i0    = strip * 6;
    const int plo   = part ? 6 : 0;
    const int phi   = part ? 11 : 6;

    const int tid  = threadIdx.x;
    const int wave = tid >> 6, lane = tid & 63;
    const int ln15 = lane & 15, kg = lane >> 4;
    const int u0   = wave * 16;

    __shared__ float corr[8][194][11];            // jj = col+1; cols 0,193 zero

    if (tid < 176) {                               // zero pad columns once
        const int ir = tid / 22, rr = tid % 22;
        const int pj = rr % 11, jj = (rr < 11) ? 0 : 193;
        corr[ir][jj][pj] = 0.f;
    }

    float yacc[3][OC];
#pragma unroll
    for (int k = 0; k < 3; ++k)
#pragma unroll
        for (int o = 0; o < OC; ++o) yacc[k][o] = 0.f;

    const int jt  = tid % 192;                     // conv: column
    const int irb = tid / 192;                     // conv: rows irb, irb+2, irb+4

    const unsigned short* x0b = x0t + (size_t)b * HH * X0ROW;
    const unsigned short* x1b = x1t + (size_t)b * HH * X1ROW;

    for (int pi = plo; pi < phi; ++pi) {
        __syncthreads();                           // conv(pi-1) done with corr

        // ---------------- MFMA band-GEMM: 16 steps/wave ----------------
        for (int ir = 0; ir < 8; ++ir) {
            const int i = i0 - 1 + ir;
            const int r = i + 2 * pi - 10;
            const bool gv = (i >= 0) && (i < HH) && (r >= 0) && (r < HH);
            const int icl = min(max(i, 0), HH - 1);
            const int rcl = min(max(r, 0), HH - 1);
            const unsigned short* arow = x0b + (size_t)icl * X0ROW + lane * 8;
            const unsigned short* brow = x1b + (size_t)rcl * X1ROW + lane * 8;

#pragma unroll
            for (int par = 0; par < 2; ++par) {
                const unsigned short* pa = arow + (par * 6 + wave) * 2048;
                const bf16x8 a0 = *(const bf16x8*)(pa);
                const bf16x8 a1 = *(const bf16x8*)(pa + 512);
                const bf16x8 a2 = *(const bf16x8*)(pa + 1024);
                const bf16x8 a3 = *(const bf16x8*)(pa + 1536);

#pragma unroll
                for (int vtl = 0; vtl < 2; ++vtl) {
                    const unsigned short* pb =
                        brow + (par * 7 + wave + vtl) * 2048;
                    const bf16x8 b0 = *(const bf16x8*)(pb);
                    const bf16x8 b1 = *(const bf16x8*)(pb + 512);
                    const bf16x8 b2 = *(const bf16x8*)(pb + 1024);
                    const bf16x8 b3 = *(const bf16x8*)(pb + 1536);

                    f32x4 c = {0.f, 0.f, 0.f, 0.f};
                    c = __builtin_amdgcn_mfma_f32_16x16x32_bf16(a0, b0, c, 0, 0, 0);
                    c = __builtin_amdgcn_mfma_f32_16x16x32_bf16(a1, b1, c, 0, 0, 0);
                    c = __builtin_amdgcn_mfma_f32_16x16x32_bf16(a2, b2, c, 0, 0, 0);
                    c = __builtin_amdgcn_mfma_f32_16x16x32_bf16(a3, b3, c, 0, 0, 0);

                    const int v = u0 - 8 + 16 * vtl + ln15;  // x1 zeros cover v OOB
#pragma unroll
                    for (int rg = 0; rg < 4; ++rg) {
                        const int u  = u0 + kg * 4 + rg;
                        const int pj = v - u + 5;
                        if (pj >= 0 && pj < 11)
                            corr[ir][2 * u + par + 1][pj] = gv ? c[rg] : 0.f;
                    }
                }
            }
        }
        __syncthreads();                           // corr slice visible

        // ---------------- conv(3x3, 121->8), 3 px/thread ----------------
        for (int ki = 0; ki < 3; ++ki) {
            for (int kj = 0; kj < 3; ++kj) {
                float cv[3][11];
#pragma unroll
                for (int k = 0; k < 3; ++k) {
                    const float* cp = &corr[irb + 2 * k + ki][jt + kj][0];
#pragma unroll
                    for (int pj = 0; pj < 11; ++pj) cv[k][pj] = cp[pj];
                }
#pragma unroll
                for (int o = 0; o < OC; ++o) {
                    float a0 = yacc[0][o], a1 = yacc[1][o], a2 = yacc[2][o];
#pragma unroll
                    for (int pj = 0; pj < 11; ++pj) {
                        const float wv =               // wave-uniform -> s_load
                            cw[o * 1089 + (pi * 11 + pj) * 9 + ki * 3 + kj];
                        a0 = fmaf(wv, cv[0][pj], a0);
                        a1 = fmaf(wv, cv[1][pj], a1);
                        a2 = fmaf(wv, cv[2][pj], a2);
                    }
                    yacc[0][o] = a0; yacc[1][o] = a1; yacc[2][o] = a2;
                }
            }
        }
    }

    float* yp = part ? y1 : y0;
#pragma unroll
    for (int k = 0; k < 3; ++k) {
        const int irow = i0 + irb + 2 * k;
#pragma unroll
        for (int o = 0; o < OC; ++o) {
            float val = yacc[k][o];
            if (part == 0) val += cb[o];
            yp[((size_t)(b * OC + o) * HH + irow) * WW + jt] = val;
        }
    }
}

// ---------------------------------------------------------------------------
// Fallback K1 (round-1 verified fp32 path) — only if ws too small
// ---------------------------------------------------------------------------
__global__ __launch_bounds__(256) void k_corr_conv(
    const float* __restrict__ x0, const float* __restrict__ x1,
    const float* __restrict__ cw, const float* __restrict__ cb,
    float* __restrict__ y)
{
    const int b  = blockIdx.z;
    const int i0 = blockIdx.y * 14;
    const int j0 = blockIdx.x * 14;
    const int li = threadIdx.x >> 4;
    const int lj = threadIdx.x & 15;
    const int gi = i0 + li - 1;
    const int gj = j0 + lj - 1;
    const bool valid    = (gi >= 0) & (gi < HH) & (gj >= 0) & (gj < WW);
    const bool interior = (li >= 1) & (li <= 14) & (lj >= 1) & (lj <= 14)
                        & (gi < HH) & (gj < WW);

    __shared__ float corr[16][16][13];

    float yacc[OC];
#pragma unroll
    for (int o = 0; o < OC; ++o) yacc[o] = 0.f;

    const size_t bbase = (size_t)b * CC * HW;
    const float* x0p = x0 + bbase + (size_t)gi * WW + gj;

    for (int pi = 0; pi < 11; ++pi) {
        float acc[11];
#pragma unroll
        for (int k = 0; k < 11; ++k) acc[k] = 0.f;

        const int r = gi + 2 * pi - 10;
        if (valid && r >= 0 && r < HH) {
            const float* p0 = x0p;
            if (gj >= 10 && gj <= WW - 11) {
                const float* p1o = x1 + bbase + (size_t)r * WW + (gj - 10);
#pragma unroll 2
                for (int c = 0; c < CC; ++c) {
                    const float a = *p0;
#pragma unroll
                    for (int k = 0; k < 11; ++k)
                        acc[k] = fmaf(a, p1o[2 * k], acc[k]);
                    p0 += HW; p1o += HW;
                }
            } else {
                const float* p1 = x1 + bbase + (size_t)r * WW;
#pragma unroll 2
                for (int c = 0; c < CC; ++c) {
                    const float a = *p0;
#pragma unroll
                    for (int k = 0; k < 11; ++k) {
                        const int col = gj + 2 * k - 10;
                        const float v = (col >= 0 && col < WW) ? p1[col] : 0.f;
                        acc[k] = fmaf(a, v, acc[k]);
                    }
                    p0 += HW; p1 += HW;
                }
            }
        }

        __syncthreads();
#pragma unroll
        for (int k = 0; k < 11; ++k) corr[li][lj][k] = acc[k];
        __syncthreads();

        if (interior) {
#pragma unroll
            for (int ki = 0; ki < 3; ++ki) {
#pragma unroll
                for (int kj = 0; kj < 3; ++kj) {
                    float cv[11];
#pragma unroll
                    for (int k = 0; k < 11; ++k)
                        cv[k] = corr[li + ki - 1][lj + kj - 1][k];
#pragma unroll
                    for (int o = 0; o < OC; ++o) {
#pragma unroll
                        for (int k = 0; k < 11; ++k) {
                            const float wv =
                                cw[(((o * 121) + pi * 11 + k) * 3 + ki) * 3 + kj];
                            yacc[o] = fmaf(wv, cv[k], yacc[o]);
                        }
                    }
                }
            }
        }
    }

    if (interior) {
#pragma unroll
        for (int o = 0; o < OC; ++o)
            y[(size_t)(b * OC + o) * HW + (size_t)gi * WW + gj] = yacc[o] + cb[o];
    }
}

// ---------------------------------------------------------------------------
// BN stats over y0 (+ optional y1), deterministic two-stage
// ---------------------------------------------------------------------------
__global__ __launch_bounds__(256) void k_stats_partial(
    const float* __restrict__ y0, const float* __restrict__ y1, int add2,
    float* __restrict__ st)
{
    const int bid = blockIdx.x;            // b*32 + o*4 + q
    const int b = bid >> 5, rem = bid & 31;
    const int o = rem >> 2, q = rem & 3;
    const size_t off = (size_t)(b * OC + o) * (HW / 4) + q * (HW / 16);
    const float4* p0 = (const float4*)y0 + off;
    const float4* p1 = (const float4*)y1 + off;
    float s = 0.f, qq = 0.f;
    for (int t = threadIdx.x; t < HW / 16; t += 256) {
        float4 z = p0[t];
        if (add2) {
            const float4 v = p1[t];
            z.x += v.x; z.y += v.y; z.z += v.z; z.w += v.w;
        }
        s += z.x + z.y + z.z + z.w;
        qq = fmaf(z.x, z.x, qq); qq = fmaf(z.y, z.y, qq);
        qq = fmaf(z.z, z.z, qq); qq = fmaf(z.w, z.w, qq);
    }
#pragma unroll
    for (int off2 = 32; off2 > 0; off2 >>= 1) {
        s  += __shfl_down(s, off2);
        qq += __shfl_down(qq, off2);
    }
    __shared__ float ss[4], sq[4];
    const int lane = threadIdx.x & 63, wv = threadIdx.x >> 6;
    if (lane == 0) { ss[wv] = s; sq[wv] = qq; }
    __syncthreads();
    if (threadIdx.x == 0) {
        st[bid]       = ss[0] + ss[1] + ss[2] + ss[3];
        st[256 + bid] = sq[0] + sq[1] + sq[2] + sq[3];
    }
}

__global__ void k_stats_final(float* __restrict__ st,
                              const float* __restrict__ gamma,
                              const float* __restrict__ beta)
{
    const int o = threadIdx.x;
    if (o < 8) {
        float S = 0.f, Q = 0.f;
#pragma unroll
        for (int b = 0; b < 8; ++b)
#pragma unroll
            for (int q = 0; q < 4; ++q) {
                S += st[b * 32 + o * 4 + q];
                Q += st[256 + b * 32 + o * 4 + q];
            }
        const float invN = 1.f / (float)NPIX;
        const float mean = S * invN;
        const float var  = Q * invN - mean * mean;
        const float sc   = gamma[o] / sqrtf(var + 1e-5f);
        st[512 + o] = sc;
        st[520 + o] = beta[o] - mean * sc;
    }
}

__global__ __launch_bounds__(256) void k_bn_relu(
    const float* __restrict__ y0, const float* __restrict__ y1, int add2,
    const float* __restrict__ st, float* __restrict__ out)
{
    const int i = blockIdx.x * 256 + threadIdx.x;  // float4 idx, exact grid
    const int o = (i / (HW / 4)) & 7;
    const float sc = st[512 + o], sh = st[520 + o];
    float4 z = ((const float4*)y0)[i];
    if (add2) {
        const float4 v = ((const float4*)y1)[i];
        z.x += v.x; z.y += v.y; z.z += v.z; z.w += v.w;
    }
    float4 r;
    r.x = fmaxf(fmaf(z.x, sc, sh), 0.f);
    r.y = fmaxf(fmaf(z.y, sc, sh), 0.f);
    r.z = fmaxf(fmaf(z.z, sc, sh), 0.f);
    r.w = fmaxf(fmaf(z.w, sc, sh), 0.f);
    ((float4*)out)[i] = r;
}

extern "C" void kernel_launch(void* const* d_in, const int* in_sizes, int n_in,
                              void* d_out, int out_size, void* d_ws, size_t ws_size,
                              hipStream_t stream)
{
    const float* x0    = (const float*)d_in[0];
    const float* x1    = (const float*)d_in[1];
    const float* cw    = (const float*)d_in[2];
    const float* cb    = (const float*)d_in[3];
    const float* gamma = (const float*)d_in[4];
    const float* beta  = (const float*)d_in[5];
    float* out = (float*)d_out;
    float* st  = (float*)d_ws;   // stats scratch reuses ws base (x0t dead by then)

    const size_t x0bytes = (size_t)BB * HH * X0ROW * sizeof(unsigned short); // 75.5 MB
    const size_t x1bytes = (size_t)BB * HH * X1ROW * sizeof(unsigned short); // 88.1 MB
    const size_t ybytes  = (size_t)YCHUNK * sizeof(float);                   //  9.4 MB

    if (ws_size >= x0bytes + x1bytes + ybytes) {
        unsigned short* x0t = (unsigned short*)d_ws;
        unsigned short* x1t = (unsigned short*)((char*)d_ws + x0bytes);
        float* y1           = (float*)((char*)d_ws + x0bytes + x1bytes);

        k_pack<<<dim3(HH, BB, 2), 256, 0, stream>>>(x0, x1, x0t, x1t);
        k_corr_mfma_conv<<<512, 384, 0, stream>>>(x0t, x1t, cw, cb, out, y1);
        k_stats_partial<<<256, 256, 0, stream>>>(out, y1, 1, st);
        k_stats_final<<<1, 64, 0, stream>>>(st, gamma, beta);
        k_bn_relu<<<(YCHUNK / 4) / 256, 256, 0, stream>>>(out, y1, 1, st, out);
    } else {
        dim3 g1(14, 14, 8);
        k_corr_conv<<<g1, 256, 0, stream>>>(x0, x1, cw, cb, out);
        k_stats_partial<<<256, 256, 0, stream>>>(out, out, 0, st);
        k_stats_final<<<1, 64, 0, stream>>>(st, gamma, beta);
        k_bn_relu<<<(YCHUNK / 4) / 256, 256, 0, stream>>>(out, out, 0, st, out);
    }
}

// Round 7
// 530.941 us; speedup vs baseline: 1.5160x; 1.0568x over previous
//
#include <hip/hip_runtime.h>

#define HH 192
#define WW 192
#define CC 128
#define BB 8
#define HW (HH * WW)          // 36864
#define OC 8
#define NPIX (BB * HW)        // 294912 per BN channel
#define YCHUNK (OC * BB * HW) // elements per y buffer
#define X0ROW 24576           // elems per (b,row): 2par*6ut*2048
#define X1ROW 28672           // elems per (b,row): 2par*7vt*2048

typedef __attribute__((ext_vector_type(8))) short bf16x8;
typedef __attribute__((ext_vector_type(4))) float f32x4;

__device__ __forceinline__ unsigned short f2bf(float f) {
    unsigned int u = __float_as_uint(f);
    u += 0x7fffu + ((u >> 16) & 1u);          // RNE
    return (unsigned short)(u >> 16);
}
__device__ __forceinline__ float bf2f(unsigned short u) {
    return __uint_as_float(((unsigned int)u) << 16);
}

// ---------------------------------------------------------------------------
// k_pack: fp32 [b][c][h][w] -> bf16 fragment-ordered tiles (unchanged r6).
// x0t[b][i]: 12 tiles (par*6+ut) of 2048, tile=[q(4)][kg(4)][pxl(16)][e(8)].
// x1t[b][r]: 14 tiles (par*7+vt), v = 16*vt-8+pxl, zero outside [0,96).
// ---------------------------------------------------------------------------
__global__ __launch_bounds__(256) void k_pack(
    const float* __restrict__ x0, const float* __restrict__ x1,
    unsigned short* __restrict__ x0t, unsigned short* __restrict__ x1t)
{
    const int h = blockIdx.x, b = blockIdx.y, t = blockIdx.z;
    const float* src = t ? x1 : x0;
    __shared__ unsigned short lds[WW * 130];

    for (int idx = threadIdx.x; idx < CC * WW; idx += 256) {
        const int w = idx % WW, c = idx / WW;      // consecutive w per lane
        lds[w * 130 + c] = f2bf(src[((size_t)(b * CC + c) * HH + h) * WW + w]);
    }
    __syncthreads();

    if (t == 0) {
        unsigned int* dst = (unsigned int*)(x0t + (size_t)(b * HH + h) * X0ROW);
        for (int f2 = threadIdx.x; f2 < X0ROW / 2; f2 += 256) {
            const int e2  = f2 & 3;
            const int pxl = (f2 >> 2) & 15;
            const int kg  = (f2 >> 6) & 3;
            const int q   = (f2 >> 8) & 3;
            const int pu  = f2 >> 10;              // par*6 + ut
            const int ut  = pu % 6, par = pu / 6;
            const int px  = 2 * (16 * ut + pxl) + par;
            const int c   = q * 32 + kg * 8 + e2 * 2;
            const unsigned int lo = lds[px * 130 + c];
            const unsigned int hi = lds[px * 130 + c + 1];
            dst[f2] = lo | (hi << 16);
        }
    } else {
        unsigned int* dst = (unsigned int*)(x1t + (size_t)(b * HH + h) * X1ROW);
        for (int f2 = threadIdx.x; f2 < X1ROW / 2; f2 += 256) {
            const int e2  = f2 & 3;
            const int pxl = (f2 >> 2) & 15;
            const int kg  = (f2 >> 6) & 3;
            const int q   = (f2 >> 8) & 3;
            const int pv  = f2 >> 10;              // par*7 + vt
            const int vt  = pv % 7, par = pv / 7;
            const int v   = 16 * vt - 8 + pxl;
            unsigned int val = 0;
            if (v >= 0 && v < 96) {
                const int px = 2 * v + par;
                const int c  = q * 32 + kg * 8 + e2 * 2;
                val = lds[px * 130 + c] | ((unsigned int)lds[px * 130 + c + 1] << 16);
            }
            dst[f2] = val;
        }
    }
}

// ---------------------------------------------------------------------------
// K1-MFMA v7: r6 dense-fragment structure, co-residency push:
// bf16 corr LDS (34 KB), VGPR forced <=64 via launch_bounds(384,8),
// pi-split=3 -> 768 blocks = 3 blocks/CU = 18 waves/CU.
// ---------------------------------------------------------------------------
__global__ __launch_bounds__(384, 8) void k_corr_mfma_conv(
    const unsigned short* __restrict__ x0t, const unsigned short* __restrict__ x1t,
    const float* __restrict__ cw, const float* __restrict__ cb,
    float* __restrict__ y0, float* __restrict__ y1, float* __restrict__ y2)
{
    const int L = blockIdx.x;                     // 768 blocks
    const int w = (L & 7) * 96 + (L >> 3);        // bijective XCD swizzle (768=8*96)
    const int b     = w / 96;                     // image b pinned to XCD b
    const int rem   = w % 96;
    const int part  = rem >> 5;                   // 0..2, part-major within image
    const int strip = rem & 31;
    const int i0    = strip * 6;
    const int plo   = (11 * part) / 3;            // 0,3,7
    const int phi   = (11 * (part + 1)) / 3;      // 3,7,11

    const int tid  = threadIdx.x;
    const int wave = tid >> 6, lane = tid & 63;
    const int ln15 = lane & 15, kg = lane >> 4;
    const int u0   = wave * 16;

    __shared__ unsigned short corr[8][194][11];   // bf16; jj=col+1; cols 0,193 zero

    if (tid < 176) {                               // zero pad columns once
        const int ir = tid / 22, rr = tid % 22;
        const int pj = rr % 11, jj = (rr < 11) ? 0 : 193;
        corr[ir][jj][pj] = 0;
    }

    float yacc[3][OC];
#pragma unroll
    for (int k = 0; k < 3; ++k)
#pragma unroll
        for (int o = 0; o < OC; ++o) yacc[k][o] = 0.f;

    const int jt  = tid % 192;                     // conv: column
    const int irb = tid / 192;                     // conv: rows irb, irb+2, irb+4

    const unsigned short* x0b = x0t + (size_t)b * HH * X0ROW;
    const unsigned short* x1b = x1t + (size_t)b * HH * X1ROW;

    for (int pi = plo; pi < phi; ++pi) {
        __syncthreads();                           // conv(pi-1) done with corr

        // ---------------- MFMA band-GEMM: 16 steps/wave ----------------
        for (int ir = 0; ir < 8; ++ir) {
            const int i = i0 - 1 + ir;
            const int r = i + 2 * pi - 10;
            const bool gv = (i >= 0) && (i < HH) && (r >= 0) && (r < HH);
            const int icl = min(max(i, 0), HH - 1);
            const int rcl = min(max(r, 0), HH - 1);
            const unsigned short* arow = x0b + (size_t)icl * X0ROW + lane * 8;
            const unsigned short* brow = x1b + (size_t)rcl * X1ROW + lane * 8;

#pragma unroll
            for (int par = 0; par < 2; ++par) {
                const unsigned short* pa = arow + (par * 6 + wave) * 2048;
                const bf16x8 a0 = *(const bf16x8*)(pa);
                const bf16x8 a1 = *(const bf16x8*)(pa + 512);
                const bf16x8 a2 = *(const bf16x8*)(pa + 1024);
                const bf16x8 a3 = *(const bf16x8*)(pa + 1536);

#pragma unroll
                for (int vtl = 0; vtl < 2; ++vtl) {
                    const unsigned short* pb =
                        brow + (par * 7 + wave + vtl) * 2048;
                    const bf16x8 b0 = *(const bf16x8*)(pb);
                    const bf16x8 b1 = *(const bf16x8*)(pb + 512);
                    const bf16x8 b2 = *(const bf16x8*)(pb + 1024);
                    const bf16x8 b3 = *(const bf16x8*)(pb + 1536);

                    f32x4 c = {0.f, 0.f, 0.f, 0.f};
                    c = __builtin_amdgcn_mfma_f32_16x16x32_bf16(a0, b0, c, 0, 0, 0);
                    c = __builtin_amdgcn_mfma_f32_16x16x32_bf16(a1, b1, c, 0, 0, 0);
                    c = __builtin_amdgcn_mfma_f32_16x16x32_bf16(a2, b2, c, 0, 0, 0);
                    c = __builtin_amdgcn_mfma_f32_16x16x32_bf16(a3, b3, c, 0, 0, 0);

                    const int v = u0 - 8 + 16 * vtl + ln15;  // x1 zeros cover OOB v
#pragma unroll
                    for (int rg = 0; rg < 4; ++rg) {
                        const int u  = u0 + kg * 4 + rg;
                        const int pj = v - u + 5;
                        if (pj >= 0 && pj < 11)
                            corr[ir][2 * u + par + 1][pj] = f2bf(gv ? c[rg] : 0.f);
                    }
                }
            }
        }
        __syncthreads();                           // corr slice visible

        // ---------------- conv(3x3, 121->8), 3 px/thread ----------------
        for (int ki = 0; ki < 3; ++ki) {
            for (int kj = 0; kj < 3; ++kj) {
                float cv[3][11];
#pragma unroll
                for (int k = 0; k < 3; ++k) {
                    const unsigned short* cp = &corr[irb + 2 * k + ki][jt + kj][0];
#pragma unroll
                    for (int pj = 0; pj < 11; ++pj) cv[k][pj] = bf2f(cp[pj]);
                }
#pragma unroll
                for (int o = 0; o < OC; ++o) {
                    float a0 = yacc[0][o], a1 = yacc[1][o], a2 = yacc[2][o];
#pragma unroll
                    for (int pj = 0; pj < 11; ++pj) {
                        const float wv =               // wave-uniform -> s_load
                            cw[o * 1089 + (pi * 11 + pj) * 9 + ki * 3 + kj];
                        a0 = fmaf(wv, cv[0][pj], a0);
                        a1 = fmaf(wv, cv[1][pj], a1);
                        a2 = fmaf(wv, cv[2][pj], a2);
                    }
                    yacc[0][o] = a0; yacc[1][o] = a1; yacc[2][o] = a2;
                }
            }
        }
    }

    float* yp = (part == 0) ? y0 : ((part == 1) ? y1 : y2);
#pragma unroll
    for (int k = 0; k < 3; ++k) {
        const int irow = i0 + irb + 2 * k;
#pragma unroll
        for (int o = 0; o < OC; ++o) {
            float val = yacc[k][o];
            if (part == 0) val += cb[o];
            yp[((size_t)(b * OC + o) * HH + irow) * WW + jt] = val;
        }
    }
}

// ---------------------------------------------------------------------------
// Fallback K1 (round-1 verified fp32 path) — only if ws too small
// ---------------------------------------------------------------------------
__global__ __launch_bounds__(256) void k_corr_conv(
    const float* __restrict__ x0, const float* __restrict__ x1,
    const float* __restrict__ cw, const float* __restrict__ cb,
    float* __restrict__ y)
{
    const int b  = blockIdx.z;
    const int i0 = blockIdx.y * 14;
    const int j0 = blockIdx.x * 14;
    const int li = threadIdx.x >> 4;
    const int lj = threadIdx.x & 15;
    const int gi = i0 + li - 1;
    const int gj = j0 + lj - 1;
    const bool valid    = (gi >= 0) & (gi < HH) & (gj >= 0) & (gj < WW);
    const bool interior = (li >= 1) & (li <= 14) & (lj >= 1) & (lj <= 14)
                        & (gi < HH) & (gj < WW);

    __shared__ float corr[16][16][13];

    float yacc[OC];
#pragma unroll
    for (int o = 0; o < OC; ++o) yacc[o] = 0.f;

    const size_t bbase = (size_t)b * CC * HW;
    const float* x0p = x0 + bbase + (size_t)gi * WW + gj;

    for (int pi = 0; pi < 11; ++pi) {
        float acc[11];
#pragma unroll
        for (int k = 0; k < 11; ++k) acc[k] = 0.f;

        const int r = gi + 2 * pi - 10;
        if (valid && r >= 0 && r < HH) {
            const float* p0 = x0p;
            if (gj >= 10 && gj <= WW - 11) {
                const float* p1o = x1 + bbase + (size_t)r * WW + (gj - 10);
#pragma unroll 2
                for (int c = 0; c < CC; ++c) {
                    const float a = *p0;
#pragma unroll
                    for (int k = 0; k < 11; ++k)
                        acc[k] = fmaf(a, p1o[2 * k], acc[k]);
                    p0 += HW; p1o += HW;
                }
            } else {
                const float* p1 = x1 + bbase + (size_t)r * WW;
#pragma unroll 2
                for (int c = 0; c < CC; ++c) {
                    const float a = *p0;
#pragma unroll
                    for (int k = 0; k < 11; ++k) {
                        const int col = gj + 2 * k - 10;
                        const float v = (col >= 0 && col < WW) ? p1[col] : 0.f;
                        acc[k] = fmaf(a, v, acc[k]);
                    }
                    p0 += HW; p1 += HW;
                }
            }
        }

        __syncthreads();
#pragma unroll
        for (int k = 0; k < 11; ++k) corr[li][lj][k] = acc[k];
        __syncthreads();

        if (interior) {
#pragma unroll
            for (int ki = 0; ki < 3; ++ki) {
#pragma unroll
                for (int kj = 0; kj < 3; ++kj) {
                    float cv[11];
#pragma unroll
                    for (int k = 0; k < 11; ++k)
                        cv[k] = corr[li + ki - 1][lj + kj - 1][k];
#pragma unroll
                    for (int o = 0; o < OC; ++o) {
#pragma unroll
                        for (int k = 0; k < 11; ++k) {
                            const float wv =
                                cw[(((o * 121) + pi * 11 + k) * 3 + ki) * 3 + kj];
                            yacc[o] = fmaf(wv, cv[k], yacc[o]);
                        }
                    }
                }
            }
        }
    }

    if (interior) {
#pragma unroll
        for (int o = 0; o < OC; ++o)
            y[(size_t)(b * OC + o) * HW + (size_t)gi * WW + gj] = yacc[o] + cb[o];
    }
}

// ---------------------------------------------------------------------------
// BN stats over up to 3 partial-y buffers (deterministic two-stage)
// ---------------------------------------------------------------------------
__global__ __launch_bounds__(256) void k_stats_partial(
    const float* __restrict__ y0, const float* __restrict__ y1,
    const float* __restrict__ y2, int n, float* __restrict__ st)
{
    const int bid = blockIdx.x;            // b*32 + o*4 + q
    const int b = bid >> 5, rem = bid & 31;
    const int o = rem >> 2, q = rem & 3;
    const size_t off = (size_t)(b * OC + o) * (HW / 4) + q * (HW / 16);
    const float4* p0 = (const float4*)y0 + off;
    const float4* p1 = (const float4*)y1 + off;
    const float4* p2 = (const float4*)y2 + off;
    float s = 0.f, qq = 0.f;
    for (int t = threadIdx.x; t < HW / 16; t += 256) {
        float4 z = p0[t];
        if (n >= 2) {
            const float4 v = p1[t];
            z.x += v.x; z.y += v.y; z.z += v.z; z.w += v.w;
        }
        if (n >= 3) {
            const float4 v = p2[t];
            z.x += v.x; z.y += v.y; z.z += v.z; z.w += v.w;
        }
        s += z.x + z.y + z.z + z.w;
        qq = fmaf(z.x, z.x, qq); qq = fmaf(z.y, z.y, qq);
        qq = fmaf(z.z, z.z, qq); qq = fmaf(z.w, z.w, qq);
    }
#pragma unroll
    for (int off2 = 32; off2 > 0; off2 >>= 1) {
        s  += __shfl_down(s, off2);
        qq += __shfl_down(qq, off2);
    }
    __shared__ float ss[4], sq[4];
    const int lane = threadIdx.x & 63, wv = threadIdx.x >> 6;
    if (lane == 0) { ss[wv] = s; sq[wv] = qq; }
    __syncthreads();
    if (threadIdx.x == 0) {
        st[bid]       = ss[0] + ss[1] + ss[2] + ss[3];
        st[256 + bid] = sq[0] + sq[1] + sq[2] + sq[3];
    }
}

__global__ void k_stats_final(float* __restrict__ st,
                              const float* __restrict__ gamma,
                              const float* __restrict__ beta)
{
    const int o = threadIdx.x;
    if (o < 8) {
        float S = 0.f, Q = 0.f;
#pragma unroll
        for (int b = 0; b < 8; ++b)
#pragma unroll
            for (int q = 0; q < 4; ++q) {
                S += st[b * 32 + o * 4 + q];
                Q += st[256 + b * 32 + o * 4 + q];
            }
        const float invN = 1.f / (float)NPIX;
        const float mean = S * invN;
        const float var  = Q * invN - mean * mean;
        const float sc   = gamma[o] / sqrtf(var + 1e-5f);
        st[512 + o] = sc;
        st[520 + o] = beta[o] - mean * sc;
    }
}

__global__ __launch_bounds__(256) void k_bn_relu(
    const float* __restrict__ y0, const float* __restrict__ y1,
    const float* __restrict__ y2, int n,
    const float* __restrict__ st, float* __restrict__ out)
{
    const int i = blockIdx.x * 256 + threadIdx.x;  // float4 idx, exact grid
    const int o = (i / (HW / 4)) & 7;
    const float sc = st[512 + o], sh = st[520 + o];
    float4 z = ((const float4*)y0)[i];
    if (n >= 2) {
        const float4 v = ((const float4*)y1)[i];
        z.x += v.x; z.y += v.y; z.z += v.z; z.w += v.w;
    }
    if (n >= 3) {
        const float4 v = ((const float4*)y2)[i];
        z.x += v.x; z.y += v.y; z.z += v.z; z.w += v.w;
    }
    float4 r;
    r.x = fmaxf(fmaf(z.x, sc, sh), 0.f);
    r.y = fmaxf(fmaf(z.y, sc, sh), 0.f);
    r.z = fmaxf(fmaf(z.z, sc, sh), 0.f);
    r.w = fmaxf(fmaf(z.w, sc, sh), 0.f);
    ((float4*)out)[i] = r;
}

extern "C" void kernel_launch(void* const* d_in, const int* in_sizes, int n_in,
                              void* d_out, int out_size, void* d_ws, size_t ws_size,
                              hipStream_t stream)
{
    const float* x0    = (const float*)d_in[0];
    const float* x1    = (const float*)d_in[1];
    const float* cw    = (const float*)d_in[2];
    const float* cb    = (const float*)d_in[3];
    const float* gamma = (const float*)d_in[4];
    const float* beta  = (const float*)d_in[5];
    float* out = (float*)d_out;
    float* st  = (float*)d_ws;   // stats scratch reuses ws base (x0t dead by then)

    const size_t x0bytes = (size_t)BB * HH * X0ROW * sizeof(unsigned short); // 72 MiB
    const size_t x1bytes = (size_t)BB * HH * X1ROW * sizeof(unsigned short); // 84 MiB
    const size_t ybytes  = (size_t)YCHUNK * sizeof(float);                   //  9 MiB

    if (ws_size >= x0bytes + x1bytes + 2 * ybytes) {
        unsigned short* x0t = (unsigned short*)d_ws;
        unsigned short* x1t = (unsigned short*)((char*)d_ws + x0bytes);
        float* y1           = (float*)((char*)d_ws + x0bytes + x1bytes);
        float* y2           = (float*)((char*)d_ws + x0bytes + x1bytes + ybytes);

        k_pack<<<dim3(HH, BB, 2), 256, 0, stream>>>(x0, x1, x0t, x1t);
        k_corr_mfma_conv<<<768, 384, 0, stream>>>(x0t, x1t, cw, cb, out, y1, y2);
        k_stats_partial<<<256, 256, 0, stream>>>(out, y1, y2, 3, st);
        k_stats_final<<<1, 64, 0, stream>>>(st, gamma, beta);
        k_bn_relu<<<(YCHUNK / 4) / 256, 256, 0, stream>>>(out, y1, y2, 3, st, out);
    } else {
        dim3 g1(14, 14, 8);
        k_corr_conv<<<g1, 256, 0, stream>>>(x0, x1, cw, cb, out);
        k_stats_partial<<<256, 256, 0, stream>>>(out, out, out, 1, st);
        k_stats_final<<<1, 64, 0, stream>>>(st, gamma, beta);
        k_bn_relu<<<(YCHUNK / 4) / 256, 256, 0, stream>>>(out, out, out, 1, st, out);
    }
}